// Round 18
// baseline (380.369 us; speedup 1.0000x reference)
//
#include <hip/hip_runtime.h>

namespace {

constexpr int B = 64, N = 64, D = 64, E = 2 * D + 1;  // E = 129
constexpr int NBLK = 256, NTH = 512, LMAX = 8;

__device__ __forceinline__ float4 f4ld(const float* p) { return *(const float4*)p; }
__device__ __forceinline__ void f4acc(float4& a, const float4 b) {
  a.x += b.x; a.y += b.y; a.z += b.z; a.w += b.w;
}

// r14-verified grid barrier: all arrive (vmcnt drained) -> one leader per XCD
// does __threadfence (wbl2 flushes the whole XCD L2) -> all wait K leaders.
__device__ __forceinline__ void gridbar(unsigned* set, unsigned* nxcd, int lead) {
  asm volatile("s_waitcnt vmcnt(0)" ::: "memory");
  __syncthreads();
  if (threadIdx.x == 0) {
    const int g = blockIdx.x;
    unsigned* leaf  = set + (size_t)(g & 7) * 16;
    unsigned* root  = set + 8 * 16;
    unsigned* root2 = set + 9 * 16;
    __hip_atomic_fetch_add(leaf, 1u, __ATOMIC_RELAXED, __HIP_MEMORY_SCOPE_AGENT);
    if (g < 8) {
      while (__hip_atomic_load(leaf, __ATOMIC_RELAXED, __HIP_MEMORY_SCOPE_AGENT)
             < (unsigned)(NBLK / 8))
        __builtin_amdgcn_s_sleep(2);
      __hip_atomic_fetch_add(root, 1u, __ATOMIC_RELAXED, __HIP_MEMORY_SCOPE_AGENT);
    }
    while (__hip_atomic_load(root, __ATOMIC_RELAXED, __HIP_MEMORY_SCOPE_AGENT) < 8u)
      __builtin_amdgcn_s_sleep(2);
    if (lead) {
      __threadfence();
      __hip_atomic_fetch_add(root2, 1u, __ATOMIC_RELAXED, __HIP_MEMORY_SCOPE_AGENT);
    }
    const unsigned K =
        __hip_atomic_load(nxcd, __ATOMIC_RELAXED, __HIP_MEMORY_SCOPE_AGENT);
    while (__hip_atomic_load(root2, __ATOMIC_RELAXED, __HIP_MEMORY_SCOPE_AGENT) < K)
      __builtin_amdgcn_s_sleep(2);
  }
  __syncthreads();
}

__global__ __launch_bounds__(NTH) void k_fused(
    const float* __restrict__ x,   // [B][N][D]
    const float* __restrict__ ew,  // [N][N]
    const float* __restrict__ Wm,  // [L][N][N][E][D]
    const float* __restrict__ bm,  // [L][N][N][D]
    const float* __restrict__ Wu,  // [L][2D][D]
    const float* __restrict__ bu,  // [L][D]
    const float* __restrict__ Wo,  // [D][D]
    const float* __restrict__ bo,  // [D]
    float* __restrict__ out,       // [B][D]
    char* __restrict__ ws, int L)
{
  unsigned* bar  = (unsigned*)ws;           // barrier set + elect + nxcd (4KB)
  unsigned* nxcd = bar + 960;
  float* sw1G  = (float*)(ws + 4096);                       // [L][N][D][D]
  float* baseG = sw1G + (size_t)LMAX * N * D * D;           // [L][N][D]

  // --- LDS: everything for one batch ---
  __shared__ float sA[64][68];    // s (padded: 68*4B rows, bank-shift 4)
  __shared__ float agg[64][68];   // agg / s_new / scan state
  __shared__ float wuC[64 * 64];  // Wu chunk (16KB); ew staging during prep
  __shared__ uint4 nbr4L[64];
  __shared__ float degL[64], cwL[64];
  __shared__ int   cntL[64];
  __shared__ unsigned char nfullL[64 * 64];

  const int g = blockIdx.x, t = threadIdx.x;

  // ---- per-XCD leader election (r14-verified) ----
  int lead = 0;
  if (t == 0) {
    unsigned xcd = 0;
    asm volatile("s_getreg_b32 %0, hwreg(HW_REG_XCC_ID)" : "=s"(xcd));
    unsigned* elect = bar + 832 + (size_t)(xcd & 7) * 16;
    if (__hip_atomic_fetch_add(elect, 1u, __ATOMIC_RELAXED,
                               __HIP_MEMORY_SCOPE_AGENT) == 0u) {
      lead = 1;
      __hip_atomic_fetch_add(nxcd, 1u, __ATOMIC_RELAXED,
                             __HIP_MEMORY_SCOPE_AGENT);
    }
  }

  // ---- prep: adjacency tables (redundant per block; ew staged in wuC) ----
  {
#pragma unroll
    for (int r = 0; r < 2; ++r)
      ((float4*)wuC)[r * NTH + t] = ((const float4*)ew)[r * NTH + t];
    __syncthreads();
    if (t < 64) {
      float rowsum = 0.f;
      unsigned long long lo = 0ull, hi = 0ull;
      int c = 0;
      for (int j = 0; j < N; ++j) {
        const float v = wuC[t * N + j];
        rowsum += v;
        if (v > 0.f) {
          if (c < 8)       lo |= (unsigned long long)j << (c * 8);
          else if (c < 16) hi |= (unsigned long long)j << ((c - 8) * 8);
          nfullL[t * 64 + c] = (unsigned char)j;
          ++c;
        }
      }
      uint4 w4;
      w4.x = (unsigned)lo; w4.y = (unsigned)(lo >> 32);
      w4.z = (unsigned)hi; w4.w = (unsigned)(hi >> 32);
      nbr4L[t] = w4; cntL[t] = c; degL[t] = (float)c;
      float tot = rowsum;
#pragma unroll
      for (int off = 32; off >= 1; off >>= 1) tot += __shfl_xor(tot, off, 64);
      cwL[t] = rowsum / (tot + 1e-8f);
    }
    __syncthreads();
  }

  // ---- phase A: sw1/base for every (layer, node) — weights only ----
  for (int u = g; u < L * N; u += NBLK) {
    const int lw = u >> 6, i = u & 63;
    float4 a0 = {0,0,0,0}, a1 = {0,0,0,0}, bacc = {0,0,0,0};
    const int ci = cntL[i];
    for (int c2 = 0; c2 < ci; ++c2) {
      const int j2 = nfullL[i * 64 + c2];
      const float* Wp = Wm + ((size_t)((lw * N + i) * N + j2)) * (E * D);
      f4acc(a0, f4ld(Wp + (size_t)(0 * NTH + t) * 4));
      f4acc(a1, f4ld(Wp + (size_t)(1 * NTH + t) * 4));
      if (t < 16) {
        const float w = ew[i * N + j2];
        const float4 w3 = f4ld(Wp + 2 * D * D + t * 4);
        const float4 bv = f4ld(bm + (((size_t)lw * N + i) * N + j2) * D + t * 4);
        bacc.x += w * w3.x + bv.x; bacc.y += w * w3.y + bv.y;
        bacc.z += w * w3.z + bv.z; bacc.w += w * w3.w + bv.w;
      }
    }
    float* dstw = sw1G + ((size_t)lw * N + i) * (D * D);
    *(float4*)(dstw + (size_t)(0 * NTH + t) * 4) = a0;
    *(float4*)(dstw + (size_t)(1 * NTH + t) * 4) = a1;
    if (t < 16)
      *(float4*)(baseG + ((size_t)lw * N + i) * D + t * 4) = bacc;
  }

  gridbar(bar, nxcd, lead);   // the ONLY grid barrier

  if (g >= B) return;         // phase B: 64 batch-owner blocks
  const int b = g;

  // load s = x[b] into LDS
  {
    const int i = t >> 3, q = t & 7;
    const float* ps = x + ((size_t)(b * N + i)) * D + q * 8;
    *(float4*)&sA[i][q * 8]     = f4ld(ps);
    *(float4*)&sA[i][q * 8 + 4] = f4ld(ps + 4);
  }
  __syncthreads();

  const int wv = t >> 6, lane = t & 63;
  const int k4 = lane >> 4, d16 = lane & 15;

  for (int l = 0; l < L; ++l) {
    // ===== GEMV phase: agg[i][:] = sum_j s[j]@W2_ij + s[i]@sw1_i + base_i ===
    for (int i = wv; i < N; i += 8) {
      float a0 = 0.f, a1 = 0.f, a2 = 0.f, a3 = 0.f;
      const int ci = cntL[i];
      for (int e = 0; e <= ci; ++e) {
        int j;
        const float* wsrc;
        if (e < ci) {
          j = nfullL[i * 64 + e];
          wsrc = Wm + ((size_t)((l * N + i) * N + j)) * (E * D) + (size_t)D * D;
        } else {
          j = i;
          wsrc = sw1G + ((size_t)l * N + i) * (D * D);
        }
        const float* srow = &sA[j][0];
#pragma unroll
        for (int it = 0; it < 16; ++it) {
          const int k = it * 4 + k4;
          const float a = srow[k];                       // LDS broadcast
          const float4 wr = f4ld(wsrc + (size_t)k * 64 + d16 * 4);
          a0 += a * wr.x; a1 += a * wr.y; a2 += a * wr.z; a3 += a * wr.w;
        }
      }
      // reduce over k4 (lanes xor 16, 32)
      a0 += __shfl_xor(a0, 16, 64); a0 += __shfl_xor(a0, 32, 64);
      a1 += __shfl_xor(a1, 16, 64); a1 += __shfl_xor(a1, 32, 64);
      a2 += __shfl_xor(a2, 16, 64); a2 += __shfl_xor(a2, 32, 64);
      a3 += __shfl_xor(a3, 16, 64); a3 += __shfl_xor(a3, 32, 64);
      if (k4 == 0) {
        const float4 bb = f4ld(baseG + ((size_t)l * N + i) * D + d16 * 4);
        float4 v;
        v.x = a0 + bb.x; v.y = a1 + bb.y; v.z = a2 + bb.z; v.w = a3 + bb.w;
        *(float4*)&agg[i][d16 * 4] = v;
      }
    }
    // stage Wu chunk 1 (k<64)
    const float* Wul = Wu + (size_t)l * 2 * D * D;
    const float* bul = bu + (size_t)l * D;
#pragma unroll
    for (int r = 0; r < 2; ++r)
      ((float4*)wuC)[r * NTH + t] = f4ld(Wul + (size_t)(r * NTH + t) * 4);
    __syncthreads();

    // ===== update GEMM: thread (i, dq) -> 8 outputs =====
    const int i = t >> 3, dq = t & 7;
    float4 acc0 = f4ld(bul + dq * 8), acc1 = f4ld(bul + dq * 8 + 4);
#pragma unroll 4
    for (int k = 0; k < 64; ++k) {
      const float a = sA[i][k];
      const float* wr = wuC + k * 64 + dq * 8;
      const float4 w0 = f4ld(wr), w1 = f4ld(wr + 4);
      acc0.x += a * w0.x; acc0.y += a * w0.y; acc0.z += a * w0.z; acc0.w += a * w0.w;
      acc1.x += a * w1.x; acc1.y += a * w1.y; acc1.z += a * w1.z; acc1.w += a * w1.w;
    }
    __syncthreads();
#pragma unroll
    for (int r = 0; r < 2; ++r)
      ((float4*)wuC)[r * NTH + t] = f4ld(Wul + (size_t)64 * D + (size_t)(r * NTH + t) * 4);
    __syncthreads();
#pragma unroll 4
    for (int k = 0; k < 64; ++k) {
      const float a = agg[i][k];
      const float* wr = wuC + k * 64 + dq * 8;
      const float4 w0 = f4ld(wr), w1 = f4ld(wr + 4);
      acc0.x += a * w0.x; acc0.y += a * w0.y; acc0.z += a * w0.z; acc0.w += a * w0.w;
      acc1.x += a * w1.x; acc1.y += a * w1.y; acc1.z += a * w1.z; acc1.w += a * w1.w;
    }
    // residual (reads sA)
    acc0.x = 0.9f * acc0.x + 0.1f * sA[i][dq * 8 + 0];
    acc0.y = 0.9f * acc0.y + 0.1f * sA[i][dq * 8 + 1];
    acc0.z = 0.9f * acc0.z + 0.1f * sA[i][dq * 8 + 2];
    acc0.w = 0.9f * acc0.w + 0.1f * sA[i][dq * 8 + 3];
    acc1.x = 0.9f * acc1.x + 0.1f * sA[i][dq * 8 + 4];
    acc1.y = 0.9f * acc1.y + 0.1f * sA[i][dq * 8 + 5];
    acc1.z = 0.9f * acc1.z + 0.1f * sA[i][dq * 8 + 6];
    acc1.w = 0.9f * acc1.w + 0.1f * sA[i][dq * 8 + 7];
    __syncthreads();   // all agg reads done
    *(float4*)&agg[i][dq * 8]     = acc0;   // agg now = s_new (pre-scan)
    *(float4*)&agg[i][dq * 8 + 4] = acc1;
    __syncthreads();

    // ===== sequential node scan (wave 0; lane d owns column d of agg) =====
    if (t < 64) {
      const int d = t;
      uint4 w = nbr4L[0];
      int c = cntL[0];
      float dg = degL[0];
      for (int ii = 0; ii < N; ++ii) {
        uint4 wn = w; int cn = c; float dgn = dg;
        if (ii < N - 1) { wn = nbr4L[ii + 1]; cn = cntL[ii + 1]; dgn = degL[ii + 1]; }
        const unsigned wd[4] = {w.x, w.y, w.z, w.w};
        float nbv = 0.0f;
#pragma unroll
        for (int q = 0; q < 8; ++q) {
          const int idx = (int)((wd[q >> 2] >> ((q & 3) * 8)) & 63u);
          const float v = agg[idx][d];
          nbv += (q < c) ? v : 0.0f;
        }
        if (c > 8) {
#pragma unroll
          for (int q = 8; q < 16; ++q) {
            const int idx = (int)((wd[q >> 2] >> ((q & 3) * 8)) & 63u);
            const float v = agg[idx][d];
            nbv += (q < c) ? v : 0.0f;
          }
          for (int q = 16; q < c; ++q) nbv += agg[nfullL[ii * 64 + q]][d];
        }
        const float avg = nbv / fmaxf(dg, 1.0f);
        const float cur = agg[ii][d];
        agg[ii][d] = (dg > 0.0f) ? (0.95f * cur + 0.05f * avg) : cur;
        w = wn; c = cn; dg = dgn;
      }
      if (l == L - 1) {
        float gg = 0.0f;
        for (int i2 = 0; i2 < N; ++i2) gg += cwL[i2] * agg[i2][d];
        float o = bo[d];
        for (int k2 = 0; k2 < D; ++k2) o += __shfl(gg, k2, 64) * Wo[k2 * D + d];
        out[(size_t)b * D + d] = o;
      }
    }
    if (l < L - 1) {
      __syncthreads();
      // s <- scan result for next layer
      const int i2 = t >> 3, q = t & 7;
      *(float4*)&sA[i2][q * 8]     = *(const float4*)&agg[i2][q * 8];
      *(float4*)&sA[i2][q * 8 + 4] = *(const float4*)&agg[i2][q * 8 + 4];
      __syncthreads();
    }
  }
}

}  // namespace

extern "C" void kernel_launch(void* const* d_in, const int* in_sizes, int n_in,
                              void* d_out, int out_size, void* d_ws, size_t ws_size,
                              hipStream_t stream)
{
  const float* x  = (const float*)d_in[0];
  const float* ew = (const float*)d_in[1];
  const float* Wm = (const float*)d_in[2];
  const float* bm = (const float*)d_in[3];
  const float* Wu = (const float*)d_in[4];
  const float* bu = (const float*)d_in[5];
  const float* Wo = (const float*)d_in[6];
  const float* bo = (const float*)d_in[7];
  float* out = (float*)d_out;

  int L = in_sizes[2] / (N * N * E * D);  // = 3
  if (L > LMAX) L = LMAX;

  hipMemsetAsync(d_ws, 0, 4096, stream);  // zero barrier/election counters
  k_fused<<<NBLK, NTH, 0, stream>>>(x, ew, Wm, bm, Wu, bu, Wo, bo, out,
                                    (char*)d_ws, L);
}

// Round 19
// 154.242 us; speedup vs baseline: 2.4661x; 2.4661x over previous
//
#include <hip/hip_runtime.h>

namespace {

constexpr int B = 64, N = 64, D = 64, E = 2 * D + 1;  // E = 129
constexpr int NBLK = 256;   // 1 block/CU
constexpr int NTH  = 512;   // 8 waves/CU
constexpr int LMAX = 3;
constexpr size_t MAXSLOT = 1024;

using i32x2 = __attribute__((ext_vector_type(2))) int;

__device__ __forceinline__ float4 f4ld(const float* p) { return *(const float4*)p; }
__device__ __forceinline__ void f4acc(float4& a, const float4 b) {
  a.x += b.x; a.y += b.y; a.z += b.z; a.w += b.w;
}

// Atomic-transport store (r16-verified): non-returning 8B atomic swap lands at
// the device coherence point; consumers first-touch rotated buffers.
__device__ __forceinline__ void st_at8(float* p, float a, float b) {
  i32x2 v; v[0] = __float_as_int(a); v[1] = __float_as_int(b);
  asm volatile("global_atomic_swap_x2 %0, %1, off"
               :: "v"(p), "v"(v) : "memory");
}
__device__ __forceinline__ void st_at16(float* p, float4 v) {
  st_at8(p, v.x, v.y);
  st_at8(p + 2, v.z, v.w);
}

// r14-verified leader-fence barrier (for phases with big plain-store output):
// all arrive (vmcnt drained) -> one leader per XCD __threadfence (wbl2 flushes
// the whole XCD L2) -> all wait K leaders.
__device__ __forceinline__ void gridbar(unsigned* set, unsigned* nxcd, int lead) {
  asm volatile("s_waitcnt vmcnt(0)" ::: "memory");
  __syncthreads();
  if (threadIdx.x == 0) {
    const int g = blockIdx.x;
    unsigned* leaf  = set + (size_t)(g & 7) * 16;
    unsigned* root  = set + 8 * 16;
    unsigned* root2 = set + 9 * 16;
    __hip_atomic_fetch_add(leaf, 1u, __ATOMIC_RELAXED, __HIP_MEMORY_SCOPE_AGENT);
    if (g < 8) {
      while (__hip_atomic_load(leaf, __ATOMIC_RELAXED, __HIP_MEMORY_SCOPE_AGENT)
             < (unsigned)(NBLK / 8))
        __builtin_amdgcn_s_sleep(2);
      __hip_atomic_fetch_add(root, 1u, __ATOMIC_RELAXED, __HIP_MEMORY_SCOPE_AGENT);
    }
    while (__hip_atomic_load(root, __ATOMIC_RELAXED, __HIP_MEMORY_SCOPE_AGENT) < 8u)
      __builtin_amdgcn_s_sleep(2);
    if (lead) {
      __threadfence();
      __hip_atomic_fetch_add(root2, 1u, __ATOMIC_RELAXED, __HIP_MEMORY_SCOPE_AGENT);
    }
    const unsigned K =
        __hip_atomic_load(nxcd, __ATOMIC_RELAXED, __HIP_MEMORY_SCOPE_AGENT);
    while (__hip_atomic_load(root2, __ATOMIC_RELAXED, __HIP_MEMORY_SCOPE_AGENT) < K)
      __builtin_amdgcn_s_sleep(2);
  }
  __syncthreads();
}

// Arrival-only barrier (for phases whose output crossed via atomic transport).
__device__ __forceinline__ void abar(unsigned* set) {
  asm volatile("s_waitcnt vmcnt(0)" ::: "memory");
  __syncthreads();
  if (threadIdx.x == 0) {
    const int g = blockIdx.x;
    unsigned* leaf = set + (size_t)(g & 7) * 16;
    unsigned* root = set + 8 * 16;
    __hip_atomic_fetch_add(leaf, 1u, __ATOMIC_RELAXED, __HIP_MEMORY_SCOPE_AGENT);
    if (g < 8) {
      while (__hip_atomic_load(leaf, __ATOMIC_RELAXED, __HIP_MEMORY_SCOPE_AGENT)
             < (unsigned)(NBLK / 8))
        __builtin_amdgcn_s_sleep(2);
      __hip_atomic_fetch_add(root, 1u, __ATOMIC_RELAXED, __HIP_MEMORY_SCOPE_AGENT);
    }
    while (__hip_atomic_load(root, __ATOMIC_RELAXED, __HIP_MEMORY_SCOPE_AGENT) < 8u)
      __builtin_amdgcn_s_sleep(2);
  }
  __syncthreads();
}

// LDS layout (bytes). Scratch [0,48K): P1 aT(16K)+wLds(16K);
// P2 catT(32K)+wuC(16K at 32K); sb overlays catT. Tables at 48K+.
constexpr int OF_WU    = 32768;
constexpr int OF_TB    = 49152;
constexpr int OF_NBR4  = OF_TB;           // 1024
constexpr int OF_DEG   = OF_TB + 1024;
constexpr int OF_CW    = OF_TB + 1280;
constexpr int OF_CNT   = OF_TB + 1536;
constexpr int OF_RB    = OF_TB + 1792;
constexpr int OF_BTMP  = OF_TB + 2048;
constexpr int OF_NE    = OF_TB + 2304;
constexpr int OF_EI    = OF_TB + 2320;    // 2048
constexpr int OF_NFULL = OF_TB + 4368;    // 4096
constexpr int POOLSZ   = 57856;

__global__ __launch_bounds__(NTH) void k_fused(
    const float* __restrict__ x,   // [B][N][D]
    const float* __restrict__ ew,  // [N][N]
    const float* __restrict__ Wm,  // [L][N][N][E][D]
    const float* __restrict__ bm,  // [L][N][N][D]
    const float* __restrict__ Wu,  // [L][2D][D]
    const float* __restrict__ bu,  // [L][D]
    const float* __restrict__ Wo,  // [D][D]
    const float* __restrict__ bo,  // [D]
    float* __restrict__ out,       // [B][D]
    char* __restrict__ ws, int L)
{
  unsigned* bar  = (unsigned*)ws;           // 5 sets x 160u + elect + nxcd
  unsigned* nxcd = bar + 960;
  char* p = ws + 4096;
  float* sbuf0   = (float*)p; p += (size_t)B * N * D * 4;
  float* sbuf1   = (float*)p; p += (size_t)B * N * D * 4;
  float* selfm   = (float*)p; p += (size_t)LMAX * N * B * D * 4;
  float* msgBuf  = (float*)p;               // [L][MAXSLOT][B][D]

  __shared__ __align__(16) char pool[POOLSZ];
  float (*aT)[64] = (float(*)[64])pool;                 // 16KB
  float* wLds  = (float*)(pool + 16384);                // 16KB
  uint4* nbr4L = (uint4*)(pool + OF_NBR4);
  float* degL  = (float*)(pool + OF_DEG);
  float* cwL   = (float*)(pool + OF_CW);
  int*   cntL  = (int*)(pool + OF_CNT);
  int*   rbL   = (int*)(pool + OF_RB);
  float* baseTmp = (float*)(pool + OF_BTMP);
  int*   neL   = (int*)(pool + OF_NE);
  unsigned short* eiL = (unsigned short*)(pool + OF_EI);
  unsigned char* nfullL = (unsigned char*)(pool + OF_NFULL);

  const int g = blockIdx.x, t = threadIdx.x;

  // ---- per-XCD leader election (r14-verified) ----
  int lead = 0;
  if (t == 0) {
    unsigned xcd = 0;
    asm volatile("s_getreg_b32 %0, hwreg(HW_REG_XCC_ID)" : "=s"(xcd));
    unsigned* elect = bar + 832 + (size_t)(xcd & 7) * 16;
    if (__hip_atomic_fetch_add(elect, 1u, __ATOMIC_RELAXED,
                               __HIP_MEMORY_SCOPE_AGENT) == 0u) {
      lead = 1;
      __hip_atomic_fetch_add(nxcd, 1u, __ATOMIC_RELAXED,
                             __HIP_MEMORY_SCOPE_AGENT);
    }
  }

  // ---- prep: adjacency tables, redundant per block ----
  {
    float* ewL = (float*)pool;  // overlay on aT
#pragma unroll
    for (int r = 0; r < 2; ++r)
      ((float4*)ewL)[r * NTH + t] = ((const float4*)ew)[r * NTH + t];
    __syncthreads();
    if (t < 64) {
      float rowsum = 0.f; int rc = 0;
      for (int j = 0; j < N; ++j) {
        const float v = ewL[t * N + j];
        rowsum += v; rc += (v > 0.f) ? 1 : 0;
      }
      int pre = rc;
#pragma unroll
      for (int off = 1; off < 64; off <<= 1) {
        int v = __shfl_up(pre, off, 64);
        if (t >= off) pre += v;
      }
      const int base = pre - rc;
      rbL[t] = base;
      unsigned long long lo = 0ull, hi = 0ull; int c = 0;
      for (int j = 0; j < N; ++j) {
        const float v = ewL[t * N + j];
        if (v > 0.f) {
          eiL[base + c] = (unsigned short)((t << 6) | j);
          if (c < 8)       lo |= (unsigned long long)j << (c * 8);
          else if (c < 16) hi |= (unsigned long long)j << ((c - 8) * 8);
          nfullL[t * 64 + c] = (unsigned char)j;
          ++c;
        }
      }
      uint4 w4;
      w4.x = (unsigned)lo; w4.y = (unsigned)(lo >> 32);
      w4.z = (unsigned)hi; w4.w = (unsigned)(hi >> 32);
      nbr4L[t] = w4; cntL[t] = c; degL[t] = (float)c;
      float tot = rowsum;
#pragma unroll
      for (int off = 32; off >= 1; off >>= 1) tot += __shfl_xor(tot, off, 64);
      cwL[t] = rowsum / (tot + 1e-8f);
      if (t == 63) *neL = base + rc;
    }
    __syncthreads();
  }
  const int ne = *neL;

  for (int l = 0; l < L; ++l) {
    const float* scur = (l == 0) ? x : ((l & 1) ? sbuf1 : sbuf0);
    float* sout = (l & 1) ? sbuf0 : sbuf1;   // rotated: no rewrite in launch
    float* msgl  = msgBuf + (size_t)l * MAXSLOT * B * D;
    float* selfl = selfm + (size_t)l * N * B * D;
    const bool LAST = (l == L - 1);

    // ===== P1: blocks 0..63 -> self units (inline W1-sum, all layers);
    //           blocks 64..255 -> edge units (<=3 each) =====
    {
      // one unit body; LDS (aT/wLds/baseTmp) reused with block-local syncs
      auto unit = [&](int jj, const float* wsrc_edge, bool self, int i) {
        // stage A^T from scur[:, jj]
        {
          const int bb = t >> 3, q = t & 7;
          const float* ps = scur + ((size_t)(bb * N + jj)) * D + q * 8;
          const float4 v0 = f4ld(ps), v1 = f4ld(ps + 4);
          const int k0 = q * 8;
          aT[k0 + 0][bb] = v0.x; aT[k0 + 1][bb] = v0.y;
          aT[k0 + 2][bb] = v0.z; aT[k0 + 3][bb] = v0.w;
          aT[k0 + 4][bb] = v1.x; aT[k0 + 5][bb] = v1.y;
          aT[k0 + 6][bb] = v1.z; aT[k0 + 7][bb] = v1.w;
        }
        if (!self) {
#pragma unroll
          for (int r = 0; r < 2; ++r)
            *(float4*)(wLds + (r * NTH + t) * 4) =
                f4ld(wsrc_edge + (size_t)(r * NTH + t) * 4);
        } else {
          // inline W1-sum over neighbors + base (weights read-only)
          float4 a0 = {0,0,0,0}, a1 = {0,0,0,0}, bacc = {0,0,0,0};
          const int ci = cntL[i];
          for (int c2 = 0; c2 < ci; ++c2) {
            const int j2 = nfullL[i * 64 + c2];
            const float* Wp = Wm + ((size_t)((l * N + i) * N + j2)) * (E * D);
            f4acc(a0, f4ld(Wp + (size_t)(0 * NTH + t) * 4));
            f4acc(a1, f4ld(Wp + (size_t)(1 * NTH + t) * 4));
            if (t < 16) {
              const float w = ew[i * N + j2];
              const float4 w3 = f4ld(Wp + 2 * D * D + t * 4);
              const float4 bv = f4ld(bm + (((size_t)l * N + i) * N + j2) * D + t * 4);
              bacc.x += w * w3.x + bv.x; bacc.y += w * w3.y + bv.y;
              bacc.z += w * w3.z + bv.z; bacc.w += w * w3.w + bv.w;
            }
          }
          *(float4*)(wLds + (0 * NTH + t) * 4) = a0;
          *(float4*)(wLds + (1 * NTH + t) * 4) = a1;
          if (t < 16) *(float4*)(baseTmp + t * 4) = bacc;
        }
        __syncthreads();

        const int td = t & 15, tr = t >> 4;
        float acc[2][4];
        if (self) {
          const float4 bv = f4ld(baseTmp + td * 4);
#pragma unroll
          for (int r = 0; r < 2; ++r) {
            acc[r][0] = bv.x; acc[r][1] = bv.y;
            acc[r][2] = bv.z; acc[r][3] = bv.w;
          }
        } else {
#pragma unroll
          for (int r = 0; r < 2; ++r)
#pragma unroll
            for (int c2 = 0; c2 < 4; ++c2) acc[r][c2] = 0.f;
        }
#pragma unroll 4
        for (int k = 0; k < D; ++k) {
          const float2 a  = *(const float2*)&aT[k][tr * 2];
          const float4 wv = f4ld(wLds + k * D + td * 4);
          const float ar[2] = {a.x, a.y};
          const float wc[4] = {wv.x, wv.y, wv.z, wv.w};
#pragma unroll
          for (int r = 0; r < 2; ++r)
#pragma unroll
            for (int c2 = 0; c2 < 4; ++c2) acc[r][c2] += ar[r] * wc[c2];
        }
        float* dst = self ? (selfl + (size_t)i * B * D) : nullptr;
        return acc, dst;  // unreachable pattern; see call sites
      };
      (void)unit;  // lambda kept simple below instead

      if (g < 64) {
        // ---- self unit i = g ----
        const int i = g;
        {
          const int bb = t >> 3, q = t & 7;
          const float* ps = scur + ((size_t)(bb * N + i)) * D + q * 8;
          const float4 v0 = f4ld(ps), v1 = f4ld(ps + 4);
          const int k0 = q * 8;
          aT[k0 + 0][bb] = v0.x; aT[k0 + 1][bb] = v0.y;
          aT[k0 + 2][bb] = v0.z; aT[k0 + 3][bb] = v0.w;
          aT[k0 + 4][bb] = v1.x; aT[k0 + 5][bb] = v1.y;
          aT[k0 + 6][bb] = v1.z; aT[k0 + 7][bb] = v1.w;
        }
        {
          float4 a0 = {0,0,0,0}, a1 = {0,0,0,0}, bacc = {0,0,0,0};
          const int ci = cntL[i];
          for (int c2 = 0; c2 < ci; ++c2) {
            const int j2 = nfullL[i * 64 + c2];
            const float* Wp = Wm + ((size_t)((l * N + i) * N + j2)) * (E * D);
            f4acc(a0, f4ld(Wp + (size_t)(0 * NTH + t) * 4));
            f4acc(a1, f4ld(Wp + (size_t)(1 * NTH + t) * 4));
            if (t < 16) {
              const float w = ew[i * N + j2];
              const float4 w3 = f4ld(Wp + 2 * D * D + t * 4);
              const float4 bv = f4ld(bm + (((size_t)l * N + i) * N + j2) * D + t * 4);
              bacc.x += w * w3.x + bv.x; bacc.y += w * w3.y + bv.y;
              bacc.z += w * w3.z + bv.z; bacc.w += w * w3.w + bv.w;
            }
          }
          *(float4*)(wLds + (0 * NTH + t) * 4) = a0;
          *(float4*)(wLds + (1 * NTH + t) * 4) = a1;
          if (t < 16) *(float4*)(baseTmp + t * 4) = bacc;
        }
        __syncthreads();
        const int td = t & 15, tr = t >> 4;
        float acc[2][4];
        {
          const float4 bv = f4ld(baseTmp + td * 4);
#pragma unroll
          for (int r = 0; r < 2; ++r) {
            acc[r][0] = bv.x; acc[r][1] = bv.y;
            acc[r][2] = bv.z; acc[r][3] = bv.w;
          }
        }
#pragma unroll 4
        for (int k = 0; k < D; ++k) {
          const float2 a  = *(const float2*)&aT[k][tr * 2];
          const float4 wv = f4ld(wLds + k * D + td * 4);
          const float ar[2] = {a.x, a.y};
          const float wc[4] = {wv.x, wv.y, wv.z, wv.w};
#pragma unroll
          for (int r = 0; r < 2; ++r)
#pragma unroll
            for (int c2 = 0; c2 < 4; ++c2) acc[r][c2] += ar[r] * wc[c2];
        }
        float* mp = selfl + (size_t)i * B * D + (size_t)(tr * 2) * D + td * 4;
#pragma unroll
        for (int r = 0; r < 2; ++r)
          *(float4*)(mp + (size_t)r * D) =
              make_float4(acc[r][0], acc[r][1], acc[r][2], acc[r][3]);
        __syncthreads();
      } else {
        // ---- edge units ----
        for (int u = g - 64; u < ne; u += NBLK - 64) {
          const int e = eiL[u];
          const int jj = e & 63;
          {
            const int bb = t >> 3, q = t & 7;
            const float* ps = scur + ((size_t)(bb * N + jj)) * D + q * 8;
            const float4 v0 = f4ld(ps), v1 = f4ld(ps + 4);
            const int k0 = q * 8;
            aT[k0 + 0][bb] = v0.x; aT[k0 + 1][bb] = v0.y;
            aT[k0 + 2][bb] = v0.z; aT[k0 + 3][bb] = v0.w;
            aT[k0 + 4][bb] = v1.x; aT[k0 + 5][bb] = v1.y;
            aT[k0 + 6][bb] = v1.z; aT[k0 + 7][bb] = v1.w;
          }
          const float* wsrc = Wm + ((size_t)((l * N + (e >> 6)) * N + jj)) * (E * D) + (size_t)D * D;
#pragma unroll
          for (int r = 0; r < 2; ++r)
            *(float4*)(wLds + (r * NTH + t) * 4) =
                f4ld(wsrc + (size_t)(r * NTH + t) * 4);
          __syncthreads();

          const int td = t & 15, tr = t >> 4;
          float acc[2][4];
#pragma unroll
          for (int r = 0; r < 2; ++r)
#pragma unroll
            for (int c2 = 0; c2 < 4; ++c2) acc[r][c2] = 0.f;
#pragma unroll 4
          for (int k = 0; k < D; ++k) {
            const float2 a  = *(const float2*)&aT[k][tr * 2];
            const float4 wv = f4ld(wLds + k * D + td * 4);
            const float ar[2] = {a.x, a.y};
            const float wc[4] = {wv.x, wv.y, wv.z, wv.w};
#pragma unroll
            for (int r = 0; r < 2; ++r)
#pragma unroll
              for (int c2 = 0; c2 < 4; ++c2) acc[r][c2] += ar[r] * wc[c2];
          }
          float* mp = msgl + (size_t)u * B * D + (size_t)(tr * 2) * D + td * 4;
#pragma unroll
          for (int r = 0; r < 2; ++r)
            *(float4*)(mp + (size_t)r * D) =
                make_float4(acc[r][0], acc[r][1], acc[r][2], acc[r][3]);
          __syncthreads();
        }
      }
    }
    // pre-stage Wu chunk0 for P2 (read-only; hides in barrier wait)
    if (g < B) {
      const float* Wul = Wu + (size_t)l * 2 * D * D;
      float* wuC = (float*)(pool + OF_WU);
#pragma unroll
      for (int r = 0; r < 2; ++r)
        *(float4*)(wuC + (r * NTH + t) * 4) = f4ld(Wul + (size_t)(r * NTH + t) * 4);
    }
    gridbar(bar + (size_t)(2 * l) * 160, nxcd, lead);   // wbl2: msg + selfmsg

    // ===== P2 (blocks 0..63): update MLP + residual + scan (+ readout) =====
    if (g < B) {
      const int b = g;
      const float* Wul = Wu + (size_t)l * 2 * D * D;
      const float* bul = bu + (size_t)l * D;
      float (*catT)[64] = (float(*)[64])pool;          // 32KB
      float* wuC = (float*)(pool + OF_WU);             // 16KB chunk

      {
        const int ii = t >> 3, q = t & 7;
        const int cI = cntL[ii], rb = rbL[ii];
        float4 a4[2];
        a4[0] = f4ld(selfl + ((size_t)(ii * B + b)) * D + q * 8);
        a4[1] = f4ld(selfl + ((size_t)(ii * B + b)) * D + q * 8 + 4);
        for (int e = 0; e < cI; ++e) {
          const float* pm = msgl + ((size_t)(rb + e) * B + b) * D + q * 8;
          f4acc(a4[0], f4ld(pm));
          f4acc(a4[1], f4ld(pm + 4));
        }
        const float* ps = scur + ((size_t)(b * N + ii)) * D + q * 8;
        const float4 v0 = f4ld(ps), v1 = f4ld(ps + 4);
        const int k0 = q * 8;
        catT[k0 + 0][ii] = v0.x; catT[k0 + 1][ii] = v0.y;
        catT[k0 + 2][ii] = v0.z; catT[k0 + 3][ii] = v0.w;
        catT[k0 + 4][ii] = v1.x; catT[k0 + 5][ii] = v1.y;
        catT[k0 + 6][ii] = v1.z; catT[k0 + 7][ii] = v1.w;
        catT[D + k0 + 0][ii] = a4[0].x; catT[D + k0 + 1][ii] = a4[0].y;
        catT[D + k0 + 2][ii] = a4[0].z; catT[D + k0 + 3][ii] = a4[0].w;
        catT[D + k0 + 4][ii] = a4[1].x; catT[D + k0 + 5][ii] = a4[1].y;
        catT[D + k0 + 6][ii] = a4[1].z; catT[D + k0 + 7][ii] = a4[1].w;
      }
      __syncthreads();

      const int td = t & 15, tr = t >> 4;
      float acc[2][4];
      {
        const float4 bv = f4ld(bul + td * 4);
#pragma unroll
        for (int r = 0; r < 2; ++r) {
          acc[r][0] = bv.x; acc[r][1] = bv.y;
          acc[r][2] = bv.z; acc[r][3] = bv.w;
        }
      }
#pragma unroll 4
      for (int k = 0; k < 64; ++k) {
        const float2 a  = *(const float2*)&catT[k][tr * 2];
        const float4 wv = f4ld(wuC + k * D + td * 4);
        const float ar[2] = {a.x, a.y};
        const float wc[4] = {wv.x, wv.y, wv.z, wv.w};
#pragma unroll
        for (int r = 0; r < 2; ++r)
#pragma unroll
          for (int c2 = 0; c2 < 4; ++c2) acc[r][c2] += ar[r] * wc[c2];
      }
      __syncthreads();
#pragma unroll
      for (int r = 0; r < 2; ++r)
        *(float4*)(wuC + (r * NTH + t) * 4) =
            f4ld(Wul + (size_t)64 * D + (size_t)(r * NTH + t) * 4);
      __syncthreads();
#pragma unroll 4
      for (int k = 0; k < 64; ++k) {
        const float2 a  = *(const float2*)&catT[64 + k][tr * 2];
        const float4 wv = f4ld(wuC + k * D + td * 4);
        const float ar[2] = {a.x, a.y};
        const float wc[4] = {wv.x, wv.y, wv.z, wv.w};
#pragma unroll
        for (int r = 0; r < 2; ++r)
#pragma unroll
          for (int c2 = 0; c2 < 4; ++c2) acc[r][c2] += ar[r] * wc[c2];
      }
      // residual (reads catT), then overlay sb on catT
#pragma unroll
      for (int r = 0; r < 2; ++r)
#pragma unroll
        for (int c2 = 0; c2 < 4; ++c2)
          acc[r][c2] = 0.9f * acc[r][c2] + 0.1f * catT[td * 4 + c2][tr * 2 + r];
      __syncthreads();
      float (*sb)[65] = (float(*)[65])pool;
#pragma unroll
      for (int r = 0; r < 2; ++r)
#pragma unroll
        for (int c2 = 0; c2 < 4; ++c2)
          sb[tr * 2 + r][td * 4 + c2] = acc[r][c2];
      __syncthreads();

      // sequential node scan; lane d owns column d (wave 0)
      if (t < 64) {
        const int d = t;
        uint4 w = nbr4L[0];
        int c = cntL[0];
        float dg = degL[0];
        for (int ii = 0; ii < N; ++ii) {
          uint4 wn = w; int cn = c; float dgn = dg;
          if (ii < N - 1) { wn = nbr4L[ii + 1]; cn = cntL[ii + 1]; dgn = degL[ii + 1]; }
          const unsigned wd[4] = {w.x, w.y, w.z, w.w};
          float nb = 0.0f;
#pragma unroll
          for (int q = 0; q < 8; ++q) {
            const int idx = (int)((wd[q >> 2] >> ((q & 3) * 8)) & 63u);
            const float v = sb[idx][d];
            nb += (q < c) ? v : 0.0f;
          }
          if (c > 8) {
#pragma unroll
            for (int q = 8; q < 16; ++q) {
              const int idx = (int)((wd[q >> 2] >> ((q & 3) * 8)) & 63u);
              const float v = sb[idx][d];
              nb += (q < c) ? v : 0.0f;
            }
            for (int q = 16; q < c; ++q) nb += sb[nfullL[ii * 64 + q]][d];
          }
          const float avg = nb / fmaxf(dg, 1.0f);
          const float cur = sb[ii][d];
          sb[ii][d] = (dg > 0.0f) ? (0.95f * cur + 0.05f * avg) : cur;
          w = wn; c = cn; dg = dgn;
        }
        if (LAST) {
          float gg = 0.0f;
          for (int i2 = 0; i2 < N; ++i2) gg += cwL[i2] * sb[i2][d];
          float o = bo[d];
          for (int k2 = 0; k2 < D; ++k2) o += __shfl(gg, k2, 64) * Wo[k2 * D + d];
          out[(size_t)b * D + d] = o;
        }
      }
      if (!LAST) {
        __syncthreads();
        const int ii = t >> 3, q = t & 7;
        float* ps = sout + ((size_t)(b * N + ii)) * D + q * 8;
        float4 v0, v1;
        v0.x = sb[ii][q * 8 + 0]; v0.y = sb[ii][q * 8 + 1];
        v0.z = sb[ii][q * 8 + 2]; v0.w = sb[ii][q * 8 + 3];
        v1.x = sb[ii][q * 8 + 4]; v1.y = sb[ii][q * 8 + 5];
        v1.z = sb[ii][q * 8 + 6]; v1.w = sb[ii][q * 8 + 7];
        st_at16(ps, v0);      // atomic transport: lands at coherence point
        st_at16(ps + 4, v1);
      }
    }
    if (l < L - 1) abar(bar + (size_t)(2 * l + 1) * 160);  // arrival-only
  }
}

}  // namespace

extern "C" void kernel_launch(void* const* d_in, const int* in_sizes, int n_in,
                              void* d_out, int out_size, void* d_ws, size_t ws_size,
                              hipStream_t stream)
{
  const float* x  = (const float*)d_in[0];
  const float* ew = (const float*)d_in[1];
  const float* Wm = (const float*)d_in[2];
  const float* bm = (const float*)d_in[3];
  const float* Wu = (const float*)d_in[4];
  const float* bu = (const float*)d_in[5];
  const float* Wo = (const float*)d_in[6];
  const float* bo = (const float*)d_in[7];
  float* out = (float*)d_out;

  int L = in_sizes[2] / (N * N * E * D);  // = 3
  if (L > LMAX) L = LMAX;

  hipMemsetAsync(d_ws, 0, 4096, stream);  // zero barrier/election counters
  k_fused<<<NBLK, NTH, 0, stream>>>(x, ew, Wm, bm, Wu, bu, Wo, bo, out,
                                    (char*)d_ws, L);
}

// Round 20
// 152.851 us; speedup vs baseline: 2.4885x; 1.0091x over previous
//
#include <hip/hip_runtime.h>

namespace {

constexpr int B = 64, N = 64, D = 64, E = 2 * D + 1;  // E = 129
constexpr int NBLK = 256;   // 1 block/CU
constexpr int NTH  = 512;   // 8 waves/CU
constexpr int LMAX = 3;
constexpr size_t MAXSLOT = 1024;

using i32x2 = __attribute__((ext_vector_type(2))) int;

__device__ __forceinline__ float4 f4ld(const float* p) { return *(const float4*)p; }
__device__ __forceinline__ void f4acc(float4& a, const float4 b) {
  a.x += b.x; a.y += b.y; a.z += b.z; a.w += b.w;
}

// Atomic-transport store (r16-verified end-to-end, incl. cross-replay buffer
// reuse): non-returning 8B atomic swap executes at the device coherence point.
__device__ __forceinline__ void st_at8(float* p, float a, float b) {
  i32x2 v; v[0] = __float_as_int(a); v[1] = __float_as_int(b);
  asm volatile("global_atomic_swap_x2 %0, %1, off"
               :: "v"(p), "v"(v) : "memory");
}
__device__ __forceinline__ void st_at16(float* p, float4 v) {
  st_at8(p, v.x, v.y);
  st_at8(p + 2, v.z, v.w);
}

// r14-verified leader-fence barrier (for the big plain-store msg output):
// all arrive (vmcnt drained) -> one leader per XCD __threadfence (wbl2 flushes
// the whole XCD L2, incl. other blocks' lines) -> all wait K leaders.
__device__ __forceinline__ void gridbar(unsigned* set, unsigned* nxcd, int lead) {
  asm volatile("s_waitcnt vmcnt(0)" ::: "memory");
  __syncthreads();
  if (threadIdx.x == 0) {
    const int g = blockIdx.x;
    unsigned* leaf  = set + (size_t)(g & 7) * 16;
    unsigned* root  = set + 8 * 16;
    unsigned* root2 = set + 9 * 16;
    __hip_atomic_fetch_add(leaf, 1u, __ATOMIC_RELAXED, __HIP_MEMORY_SCOPE_AGENT);
    if (g < 8) {
      while (__hip_atomic_load(leaf, __ATOMIC_RELAXED, __HIP_MEMORY_SCOPE_AGENT)
             < (unsigned)(NBLK / 8))
        __builtin_amdgcn_s_sleep(2);
      __hip_atomic_fetch_add(root, 1u, __ATOMIC_RELAXED, __HIP_MEMORY_SCOPE_AGENT);
    }
    while (__hip_atomic_load(root, __ATOMIC_RELAXED, __HIP_MEMORY_SCOPE_AGENT) < 8u)
      __builtin_amdgcn_s_sleep(2);
    if (lead) {
      __threadfence();
      __hip_atomic_fetch_add(root2, 1u, __ATOMIC_RELAXED, __HIP_MEMORY_SCOPE_AGENT);
    }
    const unsigned K =
        __hip_atomic_load(nxcd, __ATOMIC_RELAXED, __HIP_MEMORY_SCOPE_AGENT);
    while (__hip_atomic_load(root2, __ATOMIC_RELAXED, __HIP_MEMORY_SCOPE_AGENT) < K)
      __builtin_amdgcn_s_sleep(2);
  }
  __syncthreads();
}

// Arrival-only barrier: used where all crossing data went via atomic transport.
__device__ __forceinline__ void abar(unsigned* set) {
  asm volatile("s_waitcnt vmcnt(0)" ::: "memory");
  __syncthreads();
  if (threadIdx.x == 0) {
    const int g = blockIdx.x;
    unsigned* leaf = set + (size_t)(g & 7) * 16;
    unsigned* root = set + 8 * 16;
    __hip_atomic_fetch_add(leaf, 1u, __ATOMIC_RELAXED, __HIP_MEMORY_SCOPE_AGENT);
    if (g < 8) {
      while (__hip_atomic_load(leaf, __ATOMIC_RELAXED, __HIP_MEMORY_SCOPE_AGENT)
             < (unsigned)(NBLK / 8))
        __builtin_amdgcn_s_sleep(2);
      __hip_atomic_fetch_add(root, 1u, __ATOMIC_RELAXED, __HIP_MEMORY_SCOPE_AGENT);
    }
    while (__hip_atomic_load(root, __ATOMIC_RELAXED, __HIP_MEMORY_SCOPE_AGENT) < 8u)
      __builtin_amdgcn_s_sleep(2);
  }
  __syncthreads();
}

// LDS layout (bytes). Scratch [0,48K): P1 aT(16K)+wLds(16K);
// P2 catT(32K)+wuC(16K at 32K); sb overlays catT. Tables at 48K+.
constexpr int OF_WU    = 32768;
constexpr int OF_TB    = 49152;
constexpr int OF_NBR4  = OF_TB;           // 1024
constexpr int OF_DEG   = OF_TB + 1024;
constexpr int OF_CW    = OF_TB + 1280;
constexpr int OF_CNT   = OF_TB + 1536;
constexpr int OF_RB    = OF_TB + 1792;
constexpr int OF_BTMP  = OF_TB + 2048;
constexpr int OF_NE    = OF_TB + 2304;
constexpr int OF_EI    = OF_TB + 2320;    // 2048
constexpr int OF_NFULL = OF_TB + 4368;    // 4096
constexpr int POOLSZ   = 57856;

__global__ __launch_bounds__(NTH) void k_fused(
    const float* __restrict__ x,   // [B][N][D]
    const float* __restrict__ ew,  // [N][N]
    const float* __restrict__ Wm,  // [L][N][N][E][D]
    const float* __restrict__ bm,  // [L][N][N][D]
    const float* __restrict__ Wu,  // [L][2D][D]
    const float* __restrict__ bu,  // [L][D]
    const float* __restrict__ Wo,  // [D][D]
    const float* __restrict__ bo,  // [D]
    float* __restrict__ out,       // [B][D]
    char* __restrict__ ws, int L)
{
  unsigned* bar  = (unsigned*)ws;           // 5 sets x 160u + elect + nxcd
  unsigned* nxcd = bar + 960;
  char* p = ws + 4096;
  float* sbuf0   = (float*)p; p += (size_t)B * N * D * 4;
  float* sbuf1   = (float*)p; p += (size_t)B * N * D * 4;
  float* selfm   = (float*)p; p += (size_t)LMAX * N * B * D * 4;   // per layer
  float* msgBuf  = (float*)p; p += (size_t)LMAX * MAXSLOT * B * D * 4;  // per layer
  float* sw1     = (float*)p; p += (size_t)(LMAX - 1) * N * D * D * 4;
  float* baseB   = (float*)p;               // [LMAX-1][N][D]

  __shared__ __align__(16) char pool[POOLSZ];
  float (*aT)[64] = (float(*)[64])pool;                 // 16KB
  float* wLds  = (float*)(pool + 16384);                // 16KB
  uint4* nbr4L = (uint4*)(pool + OF_NBR4);
  float* degL  = (float*)(pool + OF_DEG);
  float* cwL   = (float*)(pool + OF_CW);
  int*   cntL  = (int*)(pool + OF_CNT);
  int*   rbL   = (int*)(pool + OF_RB);
  float* baseTmp = (float*)(pool + OF_BTMP);
  int*   neL   = (int*)(pool + OF_NE);
  unsigned short* eiL = (unsigned short*)(pool + OF_EI);
  unsigned char* nfullL = (unsigned char*)(pool + OF_NFULL);

  const int g = blockIdx.x, t = threadIdx.x;

  // ---- per-XCD leader election (r14-verified) ----
  int lead = 0;
  if (t == 0) {
    unsigned xcd = 0;
    asm volatile("s_getreg_b32 %0, hwreg(HW_REG_XCC_ID)" : "=s"(xcd));
    unsigned* elect = bar + 832 + (size_t)(xcd & 7) * 16;
    if (__hip_atomic_fetch_add(elect, 1u, __ATOMIC_RELAXED,
                               __HIP_MEMORY_SCOPE_AGENT) == 0u) {
      lead = 1;
      __hip_atomic_fetch_add(nxcd, 1u, __ATOMIC_RELAXED,
                             __HIP_MEMORY_SCOPE_AGENT);
    }
  }

  // ---- prep: redundant per block, no cross-block deps ----
  {
    float* ewL = (float*)pool;  // overlay on aT
#pragma unroll
    for (int r = 0; r < 2; ++r)
      ((float4*)ewL)[r * NTH + t] = ((const float4*)ew)[r * NTH + t];
    __syncthreads();
    if (t < 64) {
      float rowsum = 0.f; int rc = 0;
      for (int j = 0; j < N; ++j) {
        const float v = ewL[t * N + j];
        rowsum += v; rc += (v > 0.f) ? 1 : 0;
      }
      int pre = rc;
#pragma unroll
      for (int off = 1; off < 64; off <<= 1) {
        int v = __shfl_up(pre, off, 64);
        if (t >= off) pre += v;
      }
      const int base = pre - rc;
      rbL[t] = base;
      unsigned long long lo = 0ull, hi = 0ull; int c = 0;
      for (int j = 0; j < N; ++j) {
        const float v = ewL[t * N + j];
        if (v > 0.f) {
          eiL[base + c] = (unsigned short)((t << 6) | j);
          if (c < 8)       lo |= (unsigned long long)j << (c * 8);
          else if (c < 16) hi |= (unsigned long long)j << ((c - 8) * 8);
          nfullL[t * 64 + c] = (unsigned char)j;
          ++c;
        }
      }
      uint4 w4;
      w4.x = (unsigned)lo; w4.y = (unsigned)(lo >> 32);
      w4.z = (unsigned)hi; w4.w = (unsigned)(hi >> 32);
      nbr4L[t] = w4; cntL[t] = c; degL[t] = (float)c;
      float tot = rowsum;
#pragma unroll
      for (int off = 32; off >= 1; off >>= 1) tot += __shfl_xor(tot, off, 64);
      cwL[t] = rowsum / (tot + 1e-8f);
      if (t == 63) *neL = base + rc;
    }
    __syncthreads();
  }
  const int ne = *neL;

  for (int l = 0; l < L; ++l) {
    const float* scur = (l == 0) ? x : ((l & 1) ? sbuf1 : sbuf0);
    float* sout = (l & 1) ? sbuf0 : sbuf1;   // rotated: no rewrite in launch
    float* msgl  = msgBuf + (size_t)l * MAXSLOT * B * D;
    float* selfl = selfm + (size_t)l * N * B * D;
    const bool LAST = (l == L - 1);

    // ===== P1: edge GEMMs (K=64) + self GEMMs, 512 threads/unit =====
    {
      const int U = ne + N;
      for (int u = g; u < U; u += NBLK) {
        const bool self = (u >= ne);
        int i, jj; float* dst;
        if (self) { i = u - ne; jj = i; dst = selfl + (size_t)i * B * D; }
        else {
          const int e = eiL[u]; i = e >> 6; jj = e & 63;
          dst = msgl + (size_t)u * B * D;
        }
        // stage A^T from scur[:, jj]
        {
          const int bb = t >> 3, q = t & 7;
          const float* ps = scur + ((size_t)(bb * N + jj)) * D + q * 8;
          const float4 v0 = f4ld(ps), v1 = f4ld(ps + 4);
          const int k0 = q * 8;
          aT[k0 + 0][bb] = v0.x; aT[k0 + 1][bb] = v0.y;
          aT[k0 + 2][bb] = v0.z; aT[k0 + 3][bb] = v0.w;
          aT[k0 + 4][bb] = v1.x; aT[k0 + 5][bb] = v1.y;
          aT[k0 + 6][bb] = v1.z; aT[k0 + 7][bb] = v1.w;
        }
        // stage W (16KB) + base
        if (!self) {
          const int e = eiL[u];
          const float* wsrc = Wm + ((size_t)((l * N + (e >> 6)) * N + (e & 63))) * (E * D) + D * D;
#pragma unroll
          for (int r = 0; r < 2; ++r)
            *(float4*)(wLds + (r * NTH + t) * 4) = f4ld(wsrc + (r * NTH + t) * 4);
        } else if (l > 0) {
          const float* wsrc = sw1 + ((size_t)(l - 1) * N + i) * D * D;
#pragma unroll
          for (int r = 0; r < 2; ++r)
            *(float4*)(wLds + (r * NTH + t) * 4) = f4ld(wsrc + (r * NTH + t) * 4);
          if (t < 16)
            *(float4*)(baseTmp + t * 4) = f4ld(baseB + ((size_t)(l - 1) * N + i) * D + t * 4);
        } else {
          // l==0 self: inline W1-sum over neighbors + base (read-only inputs)
          float4 a0 = {0,0,0,0}, a1 = {0,0,0,0};
          float4 bacc = {0,0,0,0};
          const int ci = cntL[i];
          for (int c2 = 0; c2 < ci; ++c2) {
            const int j2 = nfullL[i * 64 + c2];
            const float* Wp = Wm + ((size_t)(i * N + j2)) * (E * D);
            f4acc(a0, f4ld(Wp + (0 * NTH + t) * 4));
            f4acc(a1, f4ld(Wp + (1 * NTH + t) * 4));
            if (t < 16) {
              const float w = ew[i * N + j2];
              const float4 w3 = f4ld(Wp + 2 * D * D + t * 4);
              const float4 bv = f4ld(bm + ((size_t)(i * N + j2)) * D + t * 4);
              bacc.x += w * w3.x + bv.x; bacc.y += w * w3.y + bv.y;
              bacc.z += w * w3.z + bv.z; bacc.w += w * w3.w + bv.w;
            }
          }
          *(float4*)(wLds + (0 * NTH + t) * 4) = a0;
          *(float4*)(wLds + (1 * NTH + t) * 4) = a1;
          if (t < 16) *(float4*)(baseTmp + t * 4) = bacc;
        }
        __syncthreads();

        // 2x4 register tile: rows b = 2*tr..+2, cols d = 4*td..+4
        const int td = t & 15, tr = t >> 4;
        float acc[2][4];
        if (self) {
          const float4 bv = f4ld(baseTmp + td * 4);
#pragma unroll
          for (int r = 0; r < 2; ++r) {
            acc[r][0] = bv.x; acc[r][1] = bv.y;
            acc[r][2] = bv.z; acc[r][3] = bv.w;
          }
        } else {
#pragma unroll
          for (int r = 0; r < 2; ++r)
#pragma unroll
            for (int c2 = 0; c2 < 4; ++c2) acc[r][c2] = 0.f;
        }
#pragma unroll 4
        for (int k = 0; k < D; ++k) {
          const float2 a  = *(const float2*)&aT[k][tr * 2];
          const float4 wv = f4ld(wLds + k * D + td * 4);
          const float ar[2] = {a.x, a.y};
          const float wc[4] = {wv.x, wv.y, wv.z, wv.w};
#pragma unroll
          for (int r = 0; r < 2; ++r)
#pragma unroll
            for (int c2 = 0; c2 < 4; ++c2) acc[r][c2] += ar[r] * wc[c2];
        }
        float* mp = dst + (size_t)(tr * 2) * D + td * 4;
#pragma unroll
        for (int r = 0; r < 2; ++r)
          *(float4*)(mp + (size_t)r * D) =
              make_float4(acc[r][0], acc[r][1], acc[r][2], acc[r][3]);
        __syncthreads();  // LDS reuse by next unit
      }
    }
    // pre-stage Wu chunk0 for P2 (read-only; hides in barrier wait)
    if (g < B) {
      const float* Wul = Wu + (size_t)l * 2 * D * D;
      float* wuC = (float*)(pool + OF_WU);
#pragma unroll
      for (int r = 0; r < 2; ++r)
        *(float4*)(wuC + (r * NTH + t) * 4) = f4ld(Wul + (r * NTH + t) * 4);
    }
    gridbar(bar + (size_t)(2 * l) * 160, nxcd, lead);   // wbl2: msg + selfmsg

    // ===== P2 (blocks 0..63) || sw1/base precompute for l+1 (64..191) =====
    if (g < B) {
      const int b = g;
      const float* Wul = Wu + (size_t)l * 2 * D * D;
      const float* bul = bu + (size_t)l * D;
      float (*catT)[64] = (float(*)[64])pool;          // 32KB
      float* wuC = (float*)(pool + OF_WU);             // 16KB chunk

      {
        const int ii = t >> 3, q = t & 7;
        const int cI = cntL[ii], rb = rbL[ii];
        float4 a4[2];
        a4[0] = f4ld(selfl + ((size_t)(ii * B + b)) * D + q * 8);
        a4[1] = f4ld(selfl + ((size_t)(ii * B + b)) * D + q * 8 + 4);
        for (int e = 0; e < cI; ++e) {
          const float* pm = msgl + ((size_t)(rb + e) * B + b) * D + q * 8;
          f4acc(a4[0], f4ld(pm));
          f4acc(a4[1], f4ld(pm + 4));
        }
        const float* ps = scur + ((size_t)(b * N + ii)) * D + q * 8;
        const float4 v0 = f4ld(ps), v1 = f4ld(ps + 4);
        const int k0 = q * 8;
        catT[k0 + 0][ii] = v0.x; catT[k0 + 1][ii] = v0.y;
        catT[k0 + 2][ii] = v0.z; catT[k0 + 3][ii] = v0.w;
        catT[k0 + 4][ii] = v1.x; catT[k0 + 5][ii] = v1.y;
        catT[k0 + 6][ii] = v1.z; catT[k0 + 7][ii] = v1.w;
        catT[D + k0 + 0][ii] = a4[0].x; catT[D + k0 + 1][ii] = a4[0].y;
        catT[D + k0 + 2][ii] = a4[0].z; catT[D + k0 + 3][ii] = a4[0].w;
        catT[D + k0 + 4][ii] = a4[1].x; catT[D + k0 + 5][ii] = a4[1].y;
        catT[D + k0 + 6][ii] = a4[1].z; catT[D + k0 + 7][ii] = a4[1].w;
      }
      __syncthreads();

      // upd GEMM, 2x4 tile: rows i = 2*tr..+2, cols d = 4*td..+4
      const int td = t & 15, tr = t >> 4;
      float acc[2][4];
      {
        const float4 bv = f4ld(bul + td * 4);
#pragma unroll
        for (int r = 0; r < 2; ++r) {
          acc[r][0] = bv.x; acc[r][1] = bv.y;
          acc[r][2] = bv.z; acc[r][3] = bv.w;
        }
      }
#pragma unroll 4
      for (int k = 0; k < 64; ++k) {
        const float2 a  = *(const float2*)&catT[k][tr * 2];
        const float4 wv = f4ld(wuC + k * D + td * 4);
        const float ar[2] = {a.x, a.y};
        const float wc[4] = {wv.x, wv.y, wv.z, wv.w};
#pragma unroll
        for (int r = 0; r < 2; ++r)
#pragma unroll
          for (int c2 = 0; c2 < 4; ++c2) acc[r][c2] += ar[r] * wc[c2];
      }
      __syncthreads();
#pragma unroll
      for (int r = 0; r < 2; ++r)
        *(float4*)(wuC + (r * NTH + t) * 4) = f4ld(Wul + 64 * D + (r * NTH + t) * 4);
      __syncthreads();
#pragma unroll 4
      for (int k = 0; k < 64; ++k) {
        const float2 a  = *(const float2*)&catT[64 + k][tr * 2];
        const float4 wv = f4ld(wuC + k * D + td * 4);
        const float ar[2] = {a.x, a.y};
        const float wc[4] = {wv.x, wv.y, wv.z, wv.w};
#pragma unroll
        for (int r = 0; r < 2; ++r)
#pragma unroll
          for (int c2 = 0; c2 < 4; ++c2) acc[r][c2] += ar[r] * wc[c2];
      }
      // residual (reads catT), then overlay sb on catT
#pragma unroll
      for (int r = 0; r < 2; ++r)
#pragma unroll
        for (int c2 = 0; c2 < 4; ++c2)
          acc[r][c2] = 0.9f * acc[r][c2] + 0.1f * catT[td * 4 + c2][tr * 2 + r];
      __syncthreads();
      float (*sb)[65] = (float(*)[65])pool;
#pragma unroll
      for (int r = 0; r < 2; ++r)
#pragma unroll
        for (int c2 = 0; c2 < 4; ++c2)
          sb[tr * 2 + r][td * 4 + c2] = acc[r][c2];
      __syncthreads();

      // sequential node scan; lane d owns column d (wave 0)
      if (t < 64) {
        const int d = t;
        uint4 w = nbr4L[0];
        int c = cntL[0];
        float dg = degL[0];
        for (int ii = 0; ii < N; ++ii) {
          uint4 wn = w; int cn = c; float dgn = dg;
          if (ii < N - 1) { wn = nbr4L[ii + 1]; cn = cntL[ii + 1]; dgn = degL[ii + 1]; }
          const unsigned wd[4] = {w.x, w.y, w.z, w.w};
          float nb = 0.0f;
#pragma unroll
          for (int q = 0; q < 8; ++q) {
            const int idx = (int)((wd[q >> 2] >> ((q & 3) * 8)) & 63u);
            const float v = sb[idx][d];
            nb += (q < c) ? v : 0.0f;
          }
          if (c > 8) {
#pragma unroll
            for (int q = 8; q < 16; ++q) {
              const int idx = (int)((wd[q >> 2] >> ((q & 3) * 8)) & 63u);
              const float v = sb[idx][d];
              nb += (q < c) ? v : 0.0f;
            }
            for (int q = 16; q < c; ++q) nb += sb[nfullL[ii * 64 + q]][d];
          }
          const float avg = nb / fmaxf(dg, 1.0f);
          const float cur = sb[ii][d];
          sb[ii][d] = (dg > 0.0f) ? (0.95f * cur + 0.05f * avg) : cur;
          w = wn; c = cn; dg = dgn;
        }
        if (LAST) {
          float gg = 0.0f;
          for (int i2 = 0; i2 < N; ++i2) gg += cwL[i2] * sb[i2][d];
          float o = bo[d];
          for (int k2 = 0; k2 < D; ++k2) o += __shfl(gg, k2, 64) * Wo[k2 * D + d];
          out[(size_t)b * D + d] = o;
        }
      }
      if (!LAST) {
        __syncthreads();
        const int ii = t >> 3, q = t & 7;
        float* ps = sout + ((size_t)(b * N + ii)) * D + q * 8;
        float4 v0, v1;
        v0.x = sb[ii][q * 8 + 0]; v0.y = sb[ii][q * 8 + 1];
        v0.z = sb[ii][q * 8 + 2]; v0.w = sb[ii][q * 8 + 3];
        v1.x = sb[ii][q * 8 + 4]; v1.y = sb[ii][q * 8 + 5];
        v1.z = sb[ii][q * 8 + 6]; v1.w = sb[ii][q * 8 + 7];
        st_at16(ps, v0);      // atomic transport -> coherence point
        st_at16(ps + 4, v1);
      }
    } else if (!LAST && g >= 64 && g < 64 + 128) {
      // sw1/base half-units for layer l+1 (hidden under P2); atomic transport
      const int u = g - 64, i = u & 63, half = u >> 6;
      const int lt = l + 1;
      float4 a0 = {0,0,0,0};
      float4 bacc = {0,0,0,0};
      const int ci = cntL[i];
      for (int c2 = 0; c2 < ci; ++c2) {
        const int j2 = nfullL[i * 64 + c2];
        const float* Wp = Wm + ((size_t)((lt * N + i) * N + j2)) * (E * D);
        f4acc(a0, f4ld(Wp + (half * NTH + t) * 4));
        if (half == 0 && t < 16) {
          const float w = ew[i * N + j2];
          const float4 w3 = f4ld(Wp + 2 * D * D + t * 4);
          const float4 bv = f4ld(bm + (((size_t)lt * N + i) * N + j2) * D + t * 4);
          bacc.x += w * w3.x + bv.x; bacc.y += w * w3.y + bv.y;
          bacc.z += w * w3.z + bv.z; bacc.w += w * w3.w + bv.w;
        }
      }
      float* dstw = sw1 + ((size_t)l * N + i) * D * D;
      st_at16(dstw + (half * NTH + t) * 4, a0);
      if (half == 0 && t < 16)
        st_at16(baseB + ((size_t)l * N + i) * D + t * 4, bacc);
    }
    if (l < L - 1) abar(bar + (size_t)(2 * l + 1) * 160);  // arrival-only
  }
}

}  // namespace

extern "C" void kernel_launch(void* const* d_in, const int* in_sizes, int n_in,
                              void* d_out, int out_size, void* d_ws, size_t ws_size,
                              hipStream_t stream)
{
  const float* x  = (const float*)d_in[0];
  const float* ew = (const float*)d_in[1];
  const float* Wm = (const float*)d_in[2];
  const float* bm = (const float*)d_in[3];
  const float* Wu = (const float*)d_in[4];
  const float* bu = (const float*)d_in[5];
  const float* Wo = (const float*)d_in[6];
  const float* bo = (const float*)d_in[7];
  float* out = (float*)d_out;

  int L = in_sizes[2] / (N * N * E * D);  // = 3
  if (L > LMAX) L = LMAX;

  hipMemsetAsync(d_ws, 0, 4096, stream);  // zero barrier/election counters
  k_fused<<<NBLK, NTH, 0, stream>>>(x, ew, Wm, bm, Wu, bu, Wo, bo, out,
                                    (char*)d_ws, L);
}

// Round 21
// 149.377 us; speedup vs baseline: 2.5464x; 1.0233x over previous
//
#include <hip/hip_runtime.h>

namespace {

constexpr int B = 64, N = 64, D = 64, E = 2 * D + 1;  // E = 129
constexpr int NBLK = 256;   // 1 block/CU
constexpr int NTH  = 512;   // 8 waves/CU
constexpr int LMAX = 3;
constexpr size_t MAXSLOT = 1024;

__device__ __forceinline__ float4 f4ld(const float* p) { return *(const float4*)p; }
__device__ __forceinline__ void f4acc(float4& a, const float4 b) {
  a.x += b.x; a.y += b.y; a.z += b.z; a.w += b.w;
}

// Grid barrier with LEADER-ONLY release fence (best measured: ~20us/barrier).
// Phase 1: all 256 blocks arrive (vmcnt drained -> their stores are in their
// XCD's L2). Phase 2: one elected leader per XCD issues __threadfence()
// (wbl2 writes back the WHOLE XCD L2, incl. other blocks' lines), then bumps
// root2; everyone waits root2 == K (number of elected leaders). Consumers
// never re-read addresses they could hold stale (buffer rotation), so no
// consumer-side invalidate is required.
__device__ __forceinline__ void gridbar(unsigned* set, unsigned* nxcd, int lead) {
  asm volatile("s_waitcnt vmcnt(0)" ::: "memory");  // my stores are in L2
  __syncthreads();
  if (threadIdx.x == 0) {
    const int g = blockIdx.x;
    unsigned* leaf  = set + (size_t)(g & 7) * 16;   // 64B apart
    unsigned* root  = set + 8 * 16;
    unsigned* root2 = set + 9 * 16;
    __hip_atomic_fetch_add(leaf, 1u, __ATOMIC_RELAXED, __HIP_MEMORY_SCOPE_AGENT);
    if (g < 8) {
      while (__hip_atomic_load(leaf, __ATOMIC_RELAXED, __HIP_MEMORY_SCOPE_AGENT)
             < (unsigned)(NBLK / 8))
        __builtin_amdgcn_s_sleep(2);
      __hip_atomic_fetch_add(root, 1u, __ATOMIC_RELAXED, __HIP_MEMORY_SCOPE_AGENT);
    }
    while (__hip_atomic_load(root, __ATOMIC_RELAXED, __HIP_MEMORY_SCOPE_AGENT) < 8u)
      __builtin_amdgcn_s_sleep(2);
    if (lead) {
      __threadfence();  // wbl2: write back this XCD's L2 (all blocks' lines)
      __hip_atomic_fetch_add(root2, 1u, __ATOMIC_RELAXED, __HIP_MEMORY_SCOPE_AGENT);
    }
    const unsigned K =
        __hip_atomic_load(nxcd, __ATOMIC_RELAXED, __HIP_MEMORY_SCOPE_AGENT);
    while (__hip_atomic_load(root2, __ATOMIC_RELAXED, __HIP_MEMORY_SCOPE_AGENT) < K)
      __builtin_amdgcn_s_sleep(2);
  }
  __syncthreads();
}

// LDS layout (bytes). Scratch [0,48K): P1 aT(16K)+wLds(16K);
// P2 catT(32K)+wuC(16K at 32K); sb overlays catT. Tables at 48K+.
constexpr int OF_WU    = 32768;
constexpr int OF_TB    = 49152;
constexpr int OF_NBR4  = OF_TB;           // 1024
constexpr int OF_DEG   = OF_TB + 1024;
constexpr int OF_CW    = OF_TB + 1280;
constexpr int OF_CNT   = OF_TB + 1536;
constexpr int OF_RB    = OF_TB + 1792;
constexpr int OF_BTMP  = OF_TB + 2048;
constexpr int OF_NE    = OF_TB + 2304;
constexpr int OF_EI    = OF_TB + 2320;    // 2048
constexpr int OF_NFULL = OF_TB + 4368;    // 4096
constexpr int POOLSZ   = 57856;

__global__ __launch_bounds__(NTH) void k_fused(
    const float* __restrict__ x,   // [B][N][D]
    const float* __restrict__ ew,  // [N][N]
    const float* __restrict__ Wm,  // [L][N][N][E][D]
    const float* __restrict__ bm,  // [L][N][N][D]
    const float* __restrict__ Wu,  // [L][2D][D]
    const float* __restrict__ bu,  // [L][D]
    const float* __restrict__ Wo,  // [D][D]
    const float* __restrict__ bo,  // [D]
    float* __restrict__ out,       // [B][D]
    char* __restrict__ ws, int L)
{
  // barrier region (memset 4KB each launch):
  //   sets 0..4: 160 uints each (leaf 8x16, root, root2)  -> bytes [0,3200)
  //   elect[8]: byte 3328, stride 64B                     -> [3328,3840)
  //   nxcd:     byte 3840
  unsigned* bar  = (unsigned*)ws;
  unsigned* nxcd = bar + 960;
  char* p = ws + 4096;
  float* sbuf0   = (float*)p; p += (size_t)B * N * D * 4;
  float* sbuf1   = (float*)p; p += (size_t)B * N * D * 4;
  float* selfm   = (float*)p; p += (size_t)LMAX * N * B * D * 4;   // per layer
  float* msgBuf  = (float*)p; p += (size_t)LMAX * MAXSLOT * B * D * 4;  // per layer
  float* sw1     = (float*)p; p += (size_t)(LMAX - 1) * N * D * D * 4;
  float* baseB   = (float*)p;               // [LMAX-1][N][D]

  __shared__ __align__(16) char pool[POOLSZ];
  float (*aT)[64] = (float(*)[64])pool;                 // 16KB
  float* wLds  = (float*)(pool + 16384);                // 16KB
  uint4* nbr4L = (uint4*)(pool + OF_NBR4);
  float* degL  = (float*)(pool + OF_DEG);
  float* cwL   = (float*)(pool + OF_CW);
  int*   cntL  = (int*)(pool + OF_CNT);
  int*   rbL   = (int*)(pool + OF_RB);
  float* baseTmp = (float*)(pool + OF_BTMP);
  int*   neL   = (int*)(pool + OF_NE);
  unsigned short* eiL = (unsigned short*)(pool + OF_EI);
  unsigned char* nfullL = (unsigned char*)(pool + OF_NFULL);

  const int g = blockIdx.x, t = threadIdx.x;

  // ---- per-XCD leader election (mapping-independent, deadlock-safe) ----
  int lead = 0;
  if (t == 0) {
    unsigned xcd = 0;
    asm volatile("s_getreg_b32 %0, hwreg(HW_REG_XCC_ID)" : "=s"(xcd));
    unsigned* elect = bar + 832 + (size_t)(xcd & 7) * 16;
    if (__hip_atomic_fetch_add(elect, 1u, __ATOMIC_RELAXED,
                               __HIP_MEMORY_SCOPE_AGENT) == 0u) {
      lead = 1;
      __hip_atomic_fetch_add(nxcd, 1u, __ATOMIC_RELAXED,
                             __HIP_MEMORY_SCOPE_AGENT);
    }
  }

  // ---- prep: redundant per block, no cross-block deps ----
  {
    float* ewL = (float*)pool;  // overlay on aT
#pragma unroll
    for (int r = 0; r < 2; ++r)
      ((float4*)ewL)[r * NTH + t] = ((const float4*)ew)[r * NTH + t];
    __syncthreads();
    if (t < 64) {
      float rowsum = 0.f; int rc = 0;
      for (int j = 0; j < N; ++j) {
        const float v = ewL[t * N + j];
        rowsum += v; rc += (v > 0.f) ? 1 : 0;
      }
      int pre = rc;
#pragma unroll
      for (int off = 1; off < 64; off <<= 1) {
        int v = __shfl_up(pre, off, 64);
        if (t >= off) pre += v;
      }
      const int base = pre - rc;
      rbL[t] = base;
      unsigned long long lo = 0ull, hi = 0ull; int c = 0;
      for (int j = 0; j < N; ++j) {
        const float v = ewL[t * N + j];
        if (v > 0.f) {
          eiL[base + c] = (unsigned short)((t << 6) | j);
          if (c < 8)       lo |= (unsigned long long)j << (c * 8);
          else if (c < 16) hi |= (unsigned long long)j << ((c - 8) * 8);
          nfullL[t * 64 + c] = (unsigned char)j;
          ++c;
        }
      }
      uint4 w4;
      w4.x = (unsigned)lo; w4.y = (unsigned)(lo >> 32);
      w4.z = (unsigned)hi; w4.w = (unsigned)(hi >> 32);
      nbr4L[t] = w4; cntL[t] = c; degL[t] = (float)c;
      float tot = rowsum;
#pragma unroll
      for (int off = 32; off >= 1; off >>= 1) tot += __shfl_xor(tot, off, 64);
      cwL[t] = rowsum / (tot + 1e-8f);
      if (t == 63) *neL = base + rc;
    }
    __syncthreads();
  }
  const int ne = *neL;

  for (int l = 0; l < L; ++l) {
    const float* scur = (l == 0) ? x : ((l & 1) ? sbuf1 : sbuf0);
    float* sout = (l & 1) ? sbuf0 : sbuf1;   // alternate: no rewrite in launch
    float* msgl  = msgBuf + (size_t)l * MAXSLOT * B * D;
    float* selfl = selfm + (size_t)l * N * B * D;
    const bool LAST = (l == L - 1);

    // ===== P1: edge GEMMs (K=64) + self GEMMs, 512 threads/unit =====
    {
      const int U = ne + N;
      for (int u = g; u < U; u += NBLK) {
        const bool self = (u >= ne);
        int i, jj; float* dst;
        if (self) { i = u - ne; jj = i; dst = selfl + (size_t)i * B * D; }
        else {
          const int e = eiL[u]; i = e >> 6; jj = e & 63;
          dst = msgl + (size_t)u * B * D;
        }
        // stage A^T from scur[:, jj]
        {
          const int bb = t >> 3, q = t & 7;
          const float* ps = scur + ((size_t)(bb * N + jj)) * D + q * 8;
          const float4 v0 = f4ld(ps), v1 = f4ld(ps + 4);
          const int k0 = q * 8;
          aT[k0 + 0][bb] = v0.x; aT[k0 + 1][bb] = v0.y;
          aT[k0 + 2][bb] = v0.z; aT[k0 + 3][bb] = v0.w;
          aT[k0 + 4][bb] = v1.x; aT[k0 + 5][bb] = v1.y;
          aT[k0 + 6][bb] = v1.z; aT[k0 + 7][bb] = v1.w;
        }
        // stage W (16KB) + base
        if (!self) {
          const int e = eiL[u];
          const float* wsrc = Wm + ((size_t)((l * N + (e >> 6)) * N + (e & 63))) * (E * D) + D * D;
#pragma unroll
          for (int r = 0; r < 2; ++r)
            *(float4*)(wLds + (r * NTH + t) * 4) = f4ld(wsrc + (r * NTH + t) * 4);
        } else if (l > 0) {
          const float* wsrc = sw1 + ((size_t)(l - 1) * N + i) * D * D;
#pragma unroll
          for (int r = 0; r < 2; ++r)
            *(float4*)(wLds + (r * NTH + t) * 4) = f4ld(wsrc + (r * NTH + t) * 4);
          if (t < 16)
            *(float4*)(baseTmp + t * 4) = f4ld(baseB + ((size_t)(l - 1) * N + i) * D + t * 4);
        } else {
          // l==0 self: inline W1-sum over neighbors + base (read-only inputs)
          float4 a0 = {0,0,0,0}, a1 = {0,0,0,0};
          float4 bacc = {0,0,0,0};
          const int ci = cntL[i];
          for (int c2 = 0; c2 < ci; ++c2) {
            const int j2 = nfullL[i * 64 + c2];
            const float* Wp = Wm + ((size_t)(i * N + j2)) * (E * D);
            f4acc(a0, f4ld(Wp + (0 * NTH + t) * 4));
            f4acc(a1, f4ld(Wp + (1 * NTH + t) * 4));
            if (t < 16) {
              const float w = ew[i * N + j2];
              const float4 w3 = f4ld(Wp + 2 * D * D + t * 4);
              const float4 bv = f4ld(bm + ((size_t)(i * N + j2)) * D + t * 4);
              bacc.x += w * w3.x + bv.x; bacc.y += w * w3.y + bv.y;
              bacc.z += w * w3.z + bv.z; bacc.w += w * w3.w + bv.w;
            }
          }
          *(float4*)(wLds + (0 * NTH + t) * 4) = a0;
          *(float4*)(wLds + (1 * NTH + t) * 4) = a1;
          if (t < 16) *(float4*)(baseTmp + t * 4) = bacc;
        }
        __syncthreads();

        // 2x4 register tile: rows b = 2*tr..+2, cols d = 4*td..+4
        const int td = t & 15, tr = t >> 4;
        float acc[2][4];
        if (self) {
          const float4 bv = f4ld(baseTmp + td * 4);
#pragma unroll
          for (int r = 0; r < 2; ++r) {
            acc[r][0] = bv.x; acc[r][1] = bv.y;
            acc[r][2] = bv.z; acc[r][3] = bv.w;
          }
        } else {
#pragma unroll
          for (int r = 0; r < 2; ++r)
#pragma unroll
            for (int c2 = 0; c2 < 4; ++c2) acc[r][c2] = 0.f;
        }
#pragma unroll 4
        for (int k = 0; k < D; ++k) {
          const float2 a  = *(const float2*)&aT[k][tr * 2];
          const float4 wv = f4ld(wLds + k * D + td * 4);
          const float ar[2] = {a.x, a.y};
          const float wc[4] = {wv.x, wv.y, wv.z, wv.w};
#pragma unroll
          for (int r = 0; r < 2; ++r)
#pragma unroll
            for (int c2 = 0; c2 < 4; ++c2) acc[r][c2] += ar[r] * wc[c2];
        }
        float* mp = dst + (size_t)(tr * 2) * D + td * 4;
#pragma unroll
        for (int r = 0; r < 2; ++r)
          *(float4*)(mp + (size_t)r * D) =
              make_float4(acc[r][0], acc[r][1], acc[r][2], acc[r][3]);
        __syncthreads();  // LDS reuse by next unit
      }
    }
    // pre-stage Wu chunk0 for P2 (independent of msg; hides in barrier wait)
    if (g < B) {
      const float* Wul = Wu + (size_t)l * 2 * D * D;
      float* wuC = (float*)(pool + OF_WU);
#pragma unroll
      for (int r = 0; r < 2; ++r)
        *(float4*)(wuC + (r * NTH + t) * 4) = f4ld(Wul + (r * NTH + t) * 4);
    }
    gridbar(bar + (size_t)(2 * l) * 160, nxcd, lead);

    // ===== P2 (blocks 0..63) || sw1/base precompute for l+1 (64..191) =====
    if (g < B) {
      const int b = g;
      const float* Wul = Wu + (size_t)l * 2 * D * D;
      const float* bul = bu + (size_t)l * D;
      float (*catT)[64] = (float(*)[64])pool;          // 32KB
      float* wuC = (float*)(pool + OF_WU);             // 16KB chunk

      {
        const int ii = t >> 3, q = t & 7;
        const int cI = cntL[ii], rb = rbL[ii];
        float4 a4[2];
        a4[0] = f4ld(selfl + ((size_t)(ii * B + b)) * D + q * 8);
        a4[1] = f4ld(selfl + ((size_t)(ii * B + b)) * D + q * 8 + 4);
        for (int e = 0; e < cI; ++e) {
          const float* pm = msgl + ((size_t)(rb + e) * B + b) * D + q * 8;
          f4acc(a4[0], f4ld(pm));
          f4acc(a4[1], f4ld(pm + 4));
        }
        const float* ps = scur + ((size_t)(b * N + ii)) * D + q * 8;
        const float4 v0 = f4ld(ps), v1 = f4ld(ps + 4);
        const int k0 = q * 8;
        catT[k0 + 0][ii] = v0.x; catT[k0 + 1][ii] = v0.y;
        catT[k0 + 2][ii] = v0.z; catT[k0 + 3][ii] = v0.w;
        catT[k0 + 4][ii] = v1.x; catT[k0 + 5][ii] = v1.y;
        catT[k0 + 6][ii] = v1.z; catT[k0 + 7][ii] = v1.w;
        catT[D + k0 + 0][ii] = a4[0].x; catT[D + k0 + 1][ii] = a4[0].y;
        catT[D + k0 + 2][ii] = a4[0].z; catT[D + k0 + 3][ii] = a4[0].w;
        catT[D + k0 + 4][ii] = a4[1].x; catT[D + k0 + 5][ii] = a4[1].y;
        catT[D + k0 + 6][ii] = a4[1].z; catT[D + k0 + 7][ii] = a4[1].w;
      }
      __syncthreads();

      // upd GEMM, 2x4 tile: rows i = 2*tr..+2, cols d = 4*td..+4
      const int td = t & 15, tr = t >> 4;
      float acc[2][4];
      {
        const float4 bv = f4ld(bul + td * 4);
#pragma unroll
        for (int r = 0; r < 2; ++r) {
          acc[r][0] = bv.x; acc[r][1] = bv.y;
          acc[r][2] = bv.z; acc[r][3] = bv.w;
        }
      }
#pragma unroll 4
      for (int k = 0; k < 64; ++k) {
        const float2 a  = *(const float2*)&catT[k][tr * 2];
        const float4 wv = f4ld(wuC + k * D + td * 4);
        const float ar[2] = {a.x, a.y};
        const float wc[4] = {wv.x, wv.y, wv.z, wv.w};
#pragma unroll
        for (int r = 0; r < 2; ++r)
#pragma unroll
          for (int c2 = 0; c2 < 4; ++c2) acc[r][c2] += ar[r] * wc[c2];
      }
      __syncthreads();
#pragma unroll
      for (int r = 0; r < 2; ++r)
        *(float4*)(wuC + (r * NTH + t) * 4) = f4ld(Wul + 64 * D + (r * NTH + t) * 4);
      __syncthreads();
#pragma unroll 4
      for (int k = 0; k < 64; ++k) {
        const float2 a  = *(const float2*)&catT[64 + k][tr * 2];
        const float4 wv = f4ld(wuC + k * D + td * 4);
        const float ar[2] = {a.x, a.y};
        const float wc[4] = {wv.x, wv.y, wv.z, wv.w};
#pragma unroll
        for (int r = 0; r < 2; ++r)
#pragma unroll
          for (int c2 = 0; c2 < 4; ++c2) acc[r][c2] += ar[r] * wc[c2];
      }
      // residual (reads catT), then overlay sb on catT
#pragma unroll
      for (int r = 0; r < 2; ++r)
#pragma unroll
        for (int c2 = 0; c2 < 4; ++c2)
          acc[r][c2] = 0.9f * acc[r][c2] + 0.1f * catT[td * 4 + c2][tr * 2 + r];
      __syncthreads();
      float (*sb)[65] = (float(*)[65])pool;
#pragma unroll
      for (int r = 0; r < 2; ++r)
#pragma unroll
        for (int c2 = 0; c2 < 4; ++c2)
          sb[tr * 2 + r][td * 4 + c2] = acc[r][c2];
      __syncthreads();

      // sequential node scan; lane d owns column d (wave 0)
      if (t < 64) {
        const int d = t;
        uint4 w = nbr4L[0];
        int c = cntL[0];
        float dg = degL[0];
        for (int ii = 0; ii < N; ++ii) {
          uint4 wn = w; int cn = c; float dgn = dg;
          if (ii < N - 1) { wn = nbr4L[ii + 1]; cn = cntL[ii + 1]; dgn = degL[ii + 1]; }
          const unsigned wd[4] = {w.x, w.y, w.z, w.w};
          float nb = 0.0f;
#pragma unroll
          for (int q = 0; q < 8; ++q) {
            const int idx = (int)((wd[q >> 2] >> ((q & 3) * 8)) & 63u);
            const float v = sb[idx][d];
            nb += (q < c) ? v : 0.0f;
          }
          if (c > 8) {
#pragma unroll
            for (int q = 8; q < 16; ++q) {
              const int idx = (int)((wd[q >> 2] >> ((q & 3) * 8)) & 63u);
              const float v = sb[idx][d];
              nb += (q < c) ? v : 0.0f;
            }
            for (int q = 16; q < c; ++q) nb += sb[nfullL[ii * 64 + q]][d];
          }
          const float avg = nb / fmaxf(dg, 1.0f);
          const float cur = sb[ii][d];
          sb[ii][d] = (dg > 0.0f) ? (0.95f * cur + 0.05f * avg) : cur;
          w = wn; c = cn; dg = dgn;
        }
        if (LAST) {
          float gg = 0.0f;
          for (int i2 = 0; i2 < N; ++i2) gg += cwL[i2] * sb[i2][d];
          float o = bo[d];
          for (int k2 = 0; k2 < D; ++k2) o += __shfl(gg, k2, 64) * Wo[k2 * D + d];
          out[(size_t)b * D + d] = o;
        }
      }
      if (!LAST) {
        __syncthreads();
        const int ii = t >> 3, q = t & 7;
        float* ps = sout + ((size_t)(b * N + ii)) * D + q * 8;
        float4 v0, v1;
        v0.x = sb[ii][q * 8 + 0]; v0.y = sb[ii][q * 8 + 1];
        v0.z = sb[ii][q * 8 + 2]; v0.w = sb[ii][q * 8 + 3];
        v1.x = sb[ii][q * 8 + 4]; v1.y = sb[ii][q * 8 + 5];
        v1.z = sb[ii][q * 8 + 6]; v1.w = sb[ii][q * 8 + 7];
        *(float4*)ps = v0;
        *(float4*)(ps + 4) = v1;
      }
    } else if (!LAST && g >= 64 && g < 64 + 128) {
      // sw1/base half-units for layer l+1: u in [0,128), i = u&63, half = u>>6
      const int u = g - 64, i = u & 63, half = u >> 6;
      const int lt = l + 1;
      float4 a0 = {0,0,0,0};
      float4 bacc = {0,0,0,0};
      const int ci = cntL[i];
      for (int c2 = 0; c2 < ci; ++c2) {
        const int j2 = nfullL[i * 64 + c2];
        const float* Wp = Wm + ((size_t)((lt * N + i) * N + j2)) * (E * D);
        f4acc(a0, f4ld(Wp + (half * NTH + t) * 4));
        if (half == 0 && t < 16) {
          const float w = ew[i * N + j2];
          const float4 w3 = f4ld(Wp + 2 * D * D + t * 4);
          const float4 bv = f4ld(bm + (((size_t)lt * N + i) * N + j2) * D + t * 4);
          bacc.x += w * w3.x + bv.x; bacc.y += w * w3.y + bv.y;
          bacc.z += w * w3.z + bv.z; bacc.w += w * w3.w + bv.w;
        }
      }
      float* dstw = sw1 + ((size_t)l * N + i) * D * D;
      *(float4*)(dstw + (half * NTH + t) * 4) = a0;
      if (half == 0 && t < 16)
        *(float4*)(baseB + ((size_t)l * N + i) * D + t * 4) = bacc;
    }
    if (l < L - 1) gridbar(bar + (size_t)(2 * l + 1) * 160, nxcd, lead);
  }
}

}  // namespace

extern "C" void kernel_launch(void* const* d_in, const int* in_sizes, int n_in,
                              void* d_out, int out_size, void* d_ws, size_t ws_size,
                              hipStream_t stream)
{
  const float* x  = (const float*)d_in[0];
  const float* ew = (const float*)d_in[1];
  const float* Wm = (const float*)d_in[2];
  const float* bm = (const float*)d_in[3];
  const float* Wu = (const float*)d_in[4];
  const float* bu = (const float*)d_in[5];
  const float* Wo = (const float*)d_in[6];
  const float* bo = (const float*)d_in[7];
  float* out = (float*)d_out;

  int L = in_sizes[2] / (N * N * E * D);  // = 3
  if (L > LMAX) L = LMAX;

  hipMemsetAsync(d_ws, 0, 4096, stream);  // zero barrier/election counters
  k_fused<<<NBLK, NTH, 0, stream>>>(x, ew, Wm, bm, Wu, bu, Wo, bo, out,
                                    (char*)d_ws, L);
}